// Round 3
// baseline (618.261 us; speedup 1.0000x reference)
//
#include <hip/hip_runtime.h>
#include <hip/hip_bf16.h>

#define B64   64
#define DH    512
#define HID   4096
#define VOC   50257
#define NSTEP 4
#define HSZ   (B64*DH)
#define NRB   32
#define NLB   224
#define NCHUNK 1571   // ceil(VOC/32)

typedef __attribute__((ext_vector_type(8)))  short bf16x8;
typedef __attribute__((ext_vector_type(4)))  float f32x4;
typedef __attribute__((ext_vector_type(16))) float f32x16;
typedef __hip_bfloat16 bf16;

__device__ __forceinline__ bf16x8 ldg8(const bf16* p) {
    return *reinterpret_cast<const bf16x8*>(p);
}
__device__ __forceinline__ short f2bf(float x) {
    bf16 h = __float2bfloat16(x);
    return *reinterpret_cast<short*>(&h);
}
__device__ __forceinline__ bf16x8 cvt8(const float* p) {
    f32x4 a = *reinterpret_cast<const f32x4*>(p);
    f32x4 b = *reinterpret_cast<const f32x4*>(p + 4);
    bf16x8 r;
    r[0] = f2bf(a[0]); r[1] = f2bf(a[1]); r[2] = f2bf(a[2]); r[3] = f2bf(a[3]);
    r[4] = f2bf(b[0]); r[5] = f2bf(b[1]); r[6] = f2bf(b[2]); r[7] = f2bf(b[3]);
    return r;
}
__device__ __forceinline__ float sigmf(float x) { return 1.f / (1.f + __expf(-x)); }
__device__ __forceinline__ f32x4 mfma16(bf16x8 a, bf16x8 b, f32x4 c) {
    return __builtin_amdgcn_mfma_f32_16x16x32_bf16(a, b, c, 0, 0, 0);
}

// ---------------------------------------------------------------------------
// k_prep: convert ip_w, hs, 4 GRU weight matrices to bf16; gather embed rows
// for steps 1..3 as bf16. One 8-elem chunk per thread.
// ---------------------------------------------------------------------------
__global__ __launch_bounds__(512) void k_prep(
    const float* __restrict__ hs, const float* __restrict__ ipw,
    const float* __restrict__ wi0, const float* __restrict__ wh0,
    const float* __restrict__ wi1, const float* __restrict__ wh1,
    const float* __restrict__ embed, const int* __restrict__ tids,
    bf16* __restrict__ hsb, bf16* __restrict__ ipwb,
    bf16* __restrict__ w0i, bf16* __restrict__ w0h,
    bf16* __restrict__ w1i, bf16* __restrict__ w1h,
    bf16* __restrict__ xemb)
{
    int c = blockIdx.x * 512 + threadIdx.x;
    const float* src; bf16* dst;
    if      (c < 262144) { size_t t = c;           src = ipw + t*8; dst = ipwb + t*8; }
    else if (c < 294912) { size_t t = c - 262144;  src = hs  + t*8; dst = hsb  + t*8; }
    else if (c < 393216) { size_t t = c - 294912;  src = wi0 + t*8; dst = w0i + t*8; }
    else if (c < 491520) { size_t t = c - 393216;  src = wh0 + t*8; dst = w0h + t*8; }
    else if (c < 589824) { size_t t = c - 491520;  src = wi1 + t*8; dst = w1i + t*8; }
    else if (c < 688128) { size_t t = c - 589824;  src = wh1 + t*8; dst = w1h + t*8; }
    else {
        int t = c - 688128;              // 12288 chunks = 192 rows x 64 chunks
        int r = t >> 6, j = t & 63;      // r = (s-1)*64 + b
        int s = r >> 6, b = r & 63;
        int rid = tids[b * NSTEP + s];
        src = embed + (size_t)rid * DH + j * 8;
        dst = xemb  + (size_t)r   * DH + j * 8;
    }
    *reinterpret_cast<bf16x8*>(dst) = cvt8(src);
}

// grid barrier among the NRB recurrence blocks only
__device__ __forceinline__ void gridbar(int* bar, int phase) {
    __syncthreads();
    if (threadIdx.x == 0) {
        __threadfence();
        __hip_atomic_fetch_add(&bar[phase], 1, __ATOMIC_RELEASE, __HIP_MEMORY_SCOPE_AGENT);
        while (__hip_atomic_load(&bar[phase], __ATOMIC_ACQUIRE, __HIP_MEMORY_SCOPE_AGENT) < NRB)
            __builtin_amdgcn_s_sleep(4);
        __threadfence();
    }
    __syncthreads();
}

// ---------------------------------------------------------------------------
// k_mega: 256 blocks x 1024 threads, 1 block/CU (152KB LDS).
//  blocks 0..31  : recurrence. Block = d-tile(16). Weights w0h/w1h/w1i live in
//                  LDS (XOR-swizzled), loaded ONCE -> immune to barrier L2
//                  invalidation. gi0 = x@w_ih0 precomputed in regs. 12 active
//                  waves = 3 gates x 4 m-tiles; gate-2 wave is the epilogue
//                  owner (holds h0/h1 f32 state + n-gate accs in registers).
//                  5 grid barriers (h0 triple-buffered kills the WAR bars).
//  blocks 32..255: logits. Phase 1 (overlapped with recurrence): stream all
//                  103MB of out_w -> warms L3. Phase 2 (after DONE flag):
//                  Hbig staged in LDS (swizzled), out_w from L3, 32-col
//                  chunk per wave, 2 row-halves (acc fits 64 VGPR).
// ---------------------------------------------------------------------------
__global__ __launch_bounds__(1024) void k_mega(
    const bf16* __restrict__ hsb, const bf16* __restrict__ ipwb, const float* __restrict__ ipb,
    const bf16* __restrict__ w0i, const bf16* __restrict__ w0h,
    const float* __restrict__ bi0, const float* __restrict__ bh0,
    const bf16* __restrict__ w1i, const bf16* __restrict__ w1h,
    const float* __restrict__ bi1, const float* __restrict__ bh1,
    const bf16* __restrict__ xemb,
    bf16* __restrict__ h0b3, bf16* __restrict__ h1b, bf16* __restrict__ hbig,
    int* __restrict__ bar,
    const float* __restrict__ outw, float* __restrict__ out)
{
    __shared__ __align__(16) char smem[155648];
    int tid = threadIdx.x, w = tid >> 6, lane = tid & 63;
    int lr = lane & 15, q = lane >> 4;

    if (blockIdx.x < NRB) {
        // ======================= recurrence =======================
        float* red = (float*)smem;               // [16][4][64] (P0a only)
        float* sG  = (float*)(smem + 147456);    // [2][4][4][64]
        int d0 = blockIdx.x * 16;
        int g = w >> 2, mt = w & 3, m0 = mt * 16;
        int d = d0 + lr;
        float bR0 = bi0[d] + bh0[d],        bZ0 = bi0[DH+d] + bh0[DH+d];
        float biN0 = bi0[2*DH+d],           bhN0 = bh0[2*DH+d];
        float bR1 = bi1[d] + bh1[d],        bZ1 = bi1[DH+d] + bh1[DH+d];
        float biN1 = bi1[2*DH+d],           bhN1 = bh1[2*DH+d];
        f32x4 zero4 = {0.f, 0.f, 0.f, 0.f};
        float h0st[4] = {0,0,0,0}, h1st[4] = {0,0,0,0};

        // ---- P0a: h0 = hs @ ip_w^T + ip_b (K=4096, 4-way K-split; kc = w>>2)
        {
            int kc = w >> 2;
            const bf16* arow = hsb  + (size_t)(m0 + lr) * HID + kc * 1024 + q * 8;
            const bf16* brow = ipwb + (size_t)(d0 + lr) * HID + kc * 1024 + q * 8;
            f32x4 acc = zero4;
#pragma unroll 8
            for (int k0 = 0; k0 < 1024; k0 += 32)
                acc = mfma16(ldg8(arow + k0), ldg8(brow + k0), acc);
#pragma unroll
            for (int r = 0; r < 4; ++r) red[(w*4 + r)*64 + lane] = acc[r];
            __syncthreads();
            if (g == 2) {            // waves 8..11, mt = w&3: epilogue owners
#pragma unroll
                for (int r = 0; r < 4; ++r) {
                    float S = red[((mt    )*4 + r)*64 + lane]
                            + red[((mt + 4)*4 + r)*64 + lane]
                            + red[((mt + 8)*4 + r)*64 + lane]
                            + red[((mt +12)*4 + r)*64 + lane];
                    float v = S + ipb[d];
                    h0st[r] = v; h1st[r] = v;
                    bf16 vb = __float2bfloat16(v);
                    int row = m0 + q*4 + r;
                    h0b3[row*DH + d] = vb;     // slot 0
                    h1b[row*DH + d] = vb;      // buf 0
                }
            }
            __syncthreads();   // red region about to be overwritten by weights
        }

        // ---- weights -> LDS, XOR-swizzled rows (9216 chunks / 1024 thr = 9)
#pragma unroll
        for (int i = 0; i < 9; ++i) {
            int c = tid + 1024*i;
            int mi = c / 3072, rem = c % 3072;
            int gg = rem >> 10, r = (rem >> 6) & 15, kg = rem & 63;
            const bf16* base = (mi == 0) ? w0h : (mi == 1) ? w1h : w1i;
            const bf16* src = base + ((size_t)(gg*DH + d0 + r))*DH + kg*8;
            int dst = mi*49152 + gg*16384 + r*1024 + ((kg*16) ^ ((r & 7) << 4));
            *reinterpret_cast<bf16x8*>(smem + dst) = ldg8(src);
        }

        // ---- P0b: gi_s = x_s @ w_ih0^T (s=1..3), gate-local, kept in regs
        f32x4 gi1 = zero4, gi2 = zero4, gi3 = zero4;
        if (g < 3) {
            const bf16* wiR = w0i + (size_t)(g*DH + d0 + lr)*DH + q*8;
#pragma unroll
            for (int s = 1; s < 4; ++s) {
                const bf16* xr = xemb + (size_t)((s-1)*B64 + m0 + lr)*DH + q*8;
                f32x4 a = zero4;
#pragma unroll
                for (int k0 = 0; k0 < DH; k0 += 32)
                    a = mfma16(ldg8(xr + k0), ldg8(wiR + k0), a);
                if (s == 1) gi1 = a; else if (s == 2) gi2 = a; else gi3 = a;
            }
        }
        gridbar(bar, 0);

        // ---- 4 steps x 2 layers; h0 triple-buffered, h1 double-buffered
        int c1 = 0;
#pragma unroll
        for (int s = 0; s < NSTEP; ++s) {
            int rsl = s % 3, rsw = (s + 1) % 3;
            f32x4 giv = (s == 0) ? zero4 : (s == 1) ? gi1 : (s == 2) ? gi2 : gi3;
            f32x4 aN = zero4;
            // layer 0: gh = h0 @ w0h^T (LDS weights)
            if (g < 3) {
                const bf16* hr = h0b3 + (size_t)rsl*HSZ + (size_t)(m0 + lr)*DH + q*8;
                int bbase = g*16384 + lr*1024;
                f32x4 a = zero4;
#pragma unroll
                for (int k0 = 0; k0 < DH; k0 += 32) {
                    int off = (k0*2 + q*16) ^ ((lr & 7) << 4);
                    a = mfma16(ldg8(hr + k0),
                               *reinterpret_cast<const bf16x8*>(smem + bbase + off), a);
                }
                if (g < 2) {
#pragma unroll
                    for (int r = 0; r < 4; ++r)
                        sG[((g*4 + mt)*4 + r)*64 + lane] = a[r] + giv[r];
                } else aN = a;
            }
            __syncthreads();
            if (g == 2) {
#pragma unroll
                for (int r = 0; r < 4; ++r) {
                    float G0 = sG[((0*4 + mt)*4 + r)*64 + lane];
                    float G1 = sG[((1*4 + mt)*4 + r)*64 + lane];
                    float rg = sigmf(G0 + bR0);
                    float zg = sigmf(G1 + bZ0);
                    float ng = tanhf(giv[r] + biN0 + rg * (aN[r] + bhN0));
                    h0st[r] = (1.f - zg) * ng + zg * h0st[r];
                    h0b3[(size_t)rsw*HSZ + (m0 + q*4 + r)*DH + d] = __float2bfloat16(h0st[r]);
                }
            }
            gridbar(bar, 1 + s);
            // layer 1: gates = h1 @ w1h^T + h0new @ w1i^T (LDS weights)
            f32x4 aH = zero4, aI = zero4;
            if (g < 3) {
                const bf16* h1r = h1b  + (size_t)c1 *HSZ + (size_t)(m0 + lr)*DH + q*8;
                const bf16* h0r = h0b3 + (size_t)rsw*HSZ + (size_t)(m0 + lr)*DH + q*8;
                int bH = 49152 + g*16384 + lr*1024;
                int bI = 98304 + g*16384 + lr*1024;
#pragma unroll
                for (int k0 = 0; k0 < DH; k0 += 32) {
                    int off = (k0*2 + q*16) ^ ((lr & 7) << 4);
                    aH = mfma16(ldg8(h1r + k0),
                                *reinterpret_cast<const bf16x8*>(smem + bH + off), aH);
                    aI = mfma16(ldg8(h0r + k0),
                                *reinterpret_cast<const bf16x8*>(smem + bI + off), aI);
                }
                if (g < 2) {
#pragma unroll
                    for (int r = 0; r < 4; ++r)
                        sG[((g*4 + mt)*4 + r)*64 + lane] = aH[r] + aI[r];
                }
            }
            __syncthreads();
            if (g == 2) {
#pragma unroll
                for (int r = 0; r < 4; ++r) {
                    float G0 = sG[((0*4 + mt)*4 + r)*64 + lane];
                    float G1 = sG[((1*4 + mt)*4 + r)*64 + lane];
                    float rg = sigmf(G0 + bR1);
                    float zg = sigmf(G1 + bZ1);
                    float ng = tanhf(aI[r] + biN1 + rg * (aH[r] + bhN1));
                    h1st[r] = (1.f - zg) * ng + zg * h1st[r];
                    bf16 hvb = __float2bfloat16(h1st[r]);
                    int row = m0 + q*4 + r;
                    h1b[(size_t)(c1 ^ 1)*HSZ + row*DH + d] = hvb;
                    hbig[(size_t)(row*NSTEP + s)*DH + d] = hvb;
                }
            }
            c1 ^= 1;
            __syncthreads();   // sG WAR before next step's layer-0 writes
        }
        // DONE flag (separate cacheline from phase bars)
        if (tid == 0) {
            __threadfence();
            __hip_atomic_fetch_add(&bar[32], 1, __ATOMIC_RELEASE, __HIP_MEMORY_SCOPE_AGENT);
        }
    } else {
        // ======================= logits =======================
        int lb = blockIdx.x - NRB;      // 0..223
        // phase 1: stream out_w (103MB) -> warms L3, overlapped w/ recurrence
        {
            const f32x4* p = (const f32x4*)outw;
            float a = 0.f;
            int total = VOC * DH / 4;
            for (int i = lb*1024 + tid; i < total; i += NLB*1024) {
                f32x4 v = p[i];
                a += v[0] + v[1] + v[2] + v[3];
            }
            asm volatile("" :: "v"(a));   // keep loads live
        }
        // wait for hbig
        if (tid == 0) {
            while (__hip_atomic_load(&bar[32], __ATOMIC_ACQUIRE, __HIP_MEMORY_SCOPE_AGENT) < NRB)
                __builtin_amdgcn_s_sleep(16);
            __threadfence();
        }
        __syncthreads();
        // phase 2: out = Hbig @ out_w^T. One 32-col chunk per wave (w<8).
        int c = lb + NLB * w;
        bool have = (c < NCHUNK);
        int l32 = lane & 31, e = lane >> 5;
        int n = c * 32 + l32;
        int nr = n < VOC ? n : VOC - 1;
        const float* brow = outw + (size_t)nr * DH;
#pragma unroll
        for (int h = 0; h < 2; ++h) {
            // stage hbig rows [h*128, h*128+128) -> LDS, swizzled
#pragma unroll
            for (int i = 0; i < 8; ++i) {
                int cc = tid + 1024*i;
                int r = cc >> 6, kg = cc & 63;
                int dst = r*1024 + ((kg*16) ^ ((r & 7) << 4));
                *reinterpret_cast<bf16x8*>(smem + dst) =
                    ldg8(hbig + (size_t)(h*128 + r)*DH + kg*8);
            }
            __syncthreads();
            if (have) {
                f32x16 acc[4];
#pragma unroll
                for (int i = 0; i < 4; ++i)
#pragma unroll
                    for (int j = 0; j < 16; ++j) acc[i][j] = 0.f;
#pragma unroll 4
                for (int k0 = 0; k0 < DH; k0 += 16) {
                    bf16x8 bfrag = cvt8(brow + k0 + e*8);
#pragma unroll
                    for (int mt2 = 0; mt2 < 4; ++mt2) {
                        int r = mt2*32 + l32;
                        int off = r*1024 + ((k0*2 + e*16) ^ ((r & 7) << 4));
                        acc[mt2] = __builtin_amdgcn_mfma_f32_32x32x16_bf16(
                            *reinterpret_cast<const bf16x8*>(smem + off), bfrag, acc[mt2], 0, 0, 0);
                    }
                }
                if (n < VOC) {
#pragma unroll
                    for (int mt2 = 0; mt2 < 4; ++mt2)
#pragma unroll
                        for (int reg = 0; reg < 16; ++reg) {
                            int m = h*128 + mt2*32 + (reg & 3) + 8*(reg >> 2) + 4*e;
                            out[(size_t)m * VOC + n] = acc[mt2][reg];
                        }
                }
            }
            __syncthreads();   // before restaging next half
        }
    }
}

// ---------------------------------------------------------------------------
extern "C" void kernel_launch(void* const* d_in, const int* in_sizes, int n_in,
                              void* d_out, int out_size, void* d_ws, size_t ws_size,
                              hipStream_t stream) {
    const float* hs   = (const float*)d_in[0];
    const int*   tids = (const int*)d_in[1];
    const float* ipw  = (const float*)d_in[2];
    const float* ipb  = (const float*)d_in[3];
    const float* wih0 = (const float*)d_in[4];
    const float* whh0 = (const float*)d_in[5];
    const float* bih0 = (const float*)d_in[6];
    const float* bhh0 = (const float*)d_in[7];
    const float* wih1 = (const float*)d_in[8];
    const float* whh1 = (const float*)d_in[9];
    const float* bih1 = (const float*)d_in[10];
    const float* bhh1 = (const float*)d_in[11];
    const float* embed = (const float*)d_in[12];
    const float* outw  = (const float*)d_in[13];
    float* out = (float*)d_out;

    char* ws = (char*)d_ws;
    int*  bar  = (int*) (ws + 0);          // bars 0..4, DONE at [32]; memset
    bf16* hsb  = (bf16*)(ws + 1024);       // 64x4096        (524288 B)
    bf16* ipwb = (bf16*)(ws + 525312);     // 512x4096       (4194304 B)
    bf16* w0i  = (bf16*)(ws + 4719616);    // 1536x512       (1572864 B each)
    bf16* w0h  = (bf16*)(ws + 6292480);
    bf16* w1i  = (bf16*)(ws + 7865344);
    bf16* w1h  = (bf16*)(ws + 9438208);
    bf16* xemb = (bf16*)(ws + 11011072);   // 3x64x512       (196608 B)
    bf16* h0b3 = (bf16*)(ws + 11207680);   // [3][64x512]    (196608 B)
    bf16* h1b  = (bf16*)(ws + 11404288);   // [2][64x512]    (131072 B)
    bf16* hbig = (bf16*)(ws + 11535360);   // 256x512 bf16, row m = b*4+s

    hipMemsetAsync(bar, 0, 256, stream);

    k_prep<<<1368, 512, 0, stream>>>(hs, ipw, wih0, whh0, wih1, whh1, embed, tids,
                                     hsb, ipwb, w0i, w0h, w1i, w1h, xemb);

    k_mega<<<NRB + NLB, 1024, 0, stream>>>(hsb, ipwb, ipb,
                                           w0i, w0h, bih0, bhh0,
                                           w1i, w1h, bih1, bhh1,
                                           xemb, h0b3, h1b, hbig, bar,
                                           outw, out);
}

// Round 4
// 432.177 us; speedup vs baseline: 1.4306x; 1.4306x over previous
//
#include <hip/hip_runtime.h>
#include <hip/hip_bf16.h>

#define B64   64
#define DH    512
#define HID   4096
#define VOC   50257
#define NSTEP 4
#define HSZ   (B64*DH)
#define NRB   32

typedef __attribute__((ext_vector_type(8)))  short bf16x8;
typedef __attribute__((ext_vector_type(4)))  float f32x4;
typedef __attribute__((ext_vector_type(16))) float f32x16;
typedef __hip_bfloat16 bf16;

__device__ __forceinline__ bf16x8 ldg8(const bf16* p) {
    return *reinterpret_cast<const bf16x8*>(p);
}
__device__ __forceinline__ short f2bf(float x) {
    bf16 h = __float2bfloat16(x);
    return *reinterpret_cast<short*>(&h);
}
__device__ __forceinline__ bf16x8 cvt8(const float* p) {
    f32x4 a = *reinterpret_cast<const f32x4*>(p);
    f32x4 b = *reinterpret_cast<const f32x4*>(p + 4);
    bf16x8 r;
    r[0] = f2bf(a[0]); r[1] = f2bf(a[1]); r[2] = f2bf(a[2]); r[3] = f2bf(a[3]);
    r[4] = f2bf(b[0]); r[5] = f2bf(b[1]); r[6] = f2bf(b[2]); r[7] = f2bf(b[3]);
    return r;
}
__device__ __forceinline__ float sigmf(float x) { return 1.f / (1.f + __expf(-x)); }
__device__ __forceinline__ f32x4 mfma16(bf16x8 a, bf16x8 b, f32x4 c) {
    return __builtin_amdgcn_mfma_f32_16x16x32_bf16(a, b, c, 0, 0, 0);
}

// ---------------------------------------------------------------------------
// k_prep: convert ip_w, hs, 4 GRU weight matrices to bf16; gather embed rows
// for steps 1..3 as bf16. One 8-elem chunk per thread.
// ---------------------------------------------------------------------------
__global__ __launch_bounds__(512) void k_prep(
    const float* __restrict__ hs, const float* __restrict__ ipw,
    const float* __restrict__ wi0, const float* __restrict__ wh0,
    const float* __restrict__ wi1, const float* __restrict__ wh1,
    const float* __restrict__ embed, const int* __restrict__ tids,
    bf16* __restrict__ hsb, bf16* __restrict__ ipwb,
    bf16* __restrict__ w0i, bf16* __restrict__ w0h,
    bf16* __restrict__ w1i, bf16* __restrict__ w1h,
    bf16* __restrict__ xemb)
{
    int c = blockIdx.x * 512 + threadIdx.x;
    const float* src; bf16* dst;
    if      (c < 262144) { size_t t = c;           src = ipw + t*8; dst = ipwb + t*8; }
    else if (c < 294912) { size_t t = c - 262144;  src = hs  + t*8; dst = hsb  + t*8; }
    else if (c < 393216) { size_t t = c - 294912;  src = wi0 + t*8; dst = w0i + t*8; }
    else if (c < 491520) { size_t t = c - 393216;  src = wh0 + t*8; dst = w0h + t*8; }
    else if (c < 589824) { size_t t = c - 491520;  src = wi1 + t*8; dst = w1i + t*8; }
    else if (c < 688128) { size_t t = c - 589824;  src = wh1 + t*8; dst = w1h + t*8; }
    else {
        int t = c - 688128;              // 12288 chunks = 192 rows x 64 chunks
        int r = t >> 6, j = t & 63;      // r = (s-1)*64 + b
        int s = r >> 6, b = r & 63;
        int rid = tids[b * NSTEP + s];
        src = embed + (size_t)rid * DH + j * 8;
        dst = xemb  + (size_t)r   * DH + j * 8;
    }
    *reinterpret_cast<bf16x8*>(dst) = cvt8(src);
}

// grid barrier among NRB blocks: RELEASE add, RELAXED poll (no per-iteration
// L2 invalidate), single ACQUIRE at exit.
__device__ __forceinline__ void gridbar(int* bar, int phase) {
    __syncthreads();
    if (threadIdx.x == 0) {
        __hip_atomic_fetch_add(&bar[phase], 1, __ATOMIC_RELEASE, __HIP_MEMORY_SCOPE_AGENT);
        while (__hip_atomic_load(&bar[phase], __ATOMIC_RELAXED, __HIP_MEMORY_SCOPE_AGENT) < NRB)
            __builtin_amdgcn_s_sleep(2);
        (void)__hip_atomic_load(&bar[phase], __ATOMIC_ACQUIRE, __HIP_MEMORY_SCOPE_AGENT);
    }
    __syncthreads();
}

// ---------------------------------------------------------------------------
// k_rec: 32 blocks x 1024 threads (1/CU). Block = d-tile(16 cols).
// w0h/w1h/w1i in LDS (XOR-swizzled), loaded once. gi = x@w_ih0 precomputed in
// registers. 12 active waves = 3 gates x 4 m-tiles; gate-2 wave owns the
// epilogue (f32 h-state in registers). 5 grid barriers total: after P0 and
// one per step between layer-0 epilogue and layer-1 (h0 triple-buffered,
// h1 double-buffered -> no WAR barriers needed).
// ---------------------------------------------------------------------------
__global__ __launch_bounds__(1024) void k_rec(
    const bf16* __restrict__ hsb, const bf16* __restrict__ ipwb, const float* __restrict__ ipb,
    const bf16* __restrict__ w0i, const bf16* __restrict__ w0h,
    const float* __restrict__ bi0, const float* __restrict__ bh0,
    const bf16* __restrict__ w1i, const bf16* __restrict__ w1h,
    const float* __restrict__ bi1, const float* __restrict__ bh1,
    const bf16* __restrict__ xemb,
    bf16* __restrict__ h0b3, bf16* __restrict__ h1b, bf16* __restrict__ hbig,
    int* __restrict__ bar)
{
    __shared__ __align__(16) char smem[155648];
    int tid = threadIdx.x, w = tid >> 6, lane = tid & 63;
    int lr = lane & 15, q = lane >> 4;

    float* red = (float*)smem;               // [16][4][64] (P0a only)
    float* sG  = (float*)(smem + 147456);    // [2][4][4][64]
    int d0 = blockIdx.x * 16;
    int g = w >> 2, mt = w & 3, m0 = mt * 16;
    int d = d0 + lr;
    float bR0 = bi0[d] + bh0[d],        bZ0 = bi0[DH+d] + bh0[DH+d];
    float biN0 = bi0[2*DH+d],           bhN0 = bh0[2*DH+d];
    float bR1 = bi1[d] + bh1[d],        bZ1 = bi1[DH+d] + bh1[DH+d];
    float biN1 = bi1[2*DH+d],           bhN1 = bh1[2*DH+d];
    f32x4 zero4 = {0.f, 0.f, 0.f, 0.f};
    float h0st[4] = {0,0,0,0}, h1st[4] = {0,0,0,0};

    // ---- P0a: h0 = hs @ ip_w^T + ip_b (K=4096, 4-way K-split; kc = w>>2)
    {
        int kc = w >> 2;
        const bf16* arow = hsb  + (size_t)(m0 + lr) * HID + kc * 1024 + q * 8;
        const bf16* brow = ipwb + (size_t)(d0 + lr) * HID + kc * 1024 + q * 8;
        f32x4 acc = zero4;
#pragma unroll 8
        for (int k0 = 0; k0 < 1024; k0 += 32)
            acc = mfma16(ldg8(arow + k0), ldg8(brow + k0), acc);
#pragma unroll
        for (int r = 0; r < 4; ++r) red[(w*4 + r)*64 + lane] = acc[r];
        __syncthreads();
        if (g == 2) {            // waves 8..11: epilogue owners
#pragma unroll
            for (int r = 0; r < 4; ++r) {
                float S = red[((mt    )*4 + r)*64 + lane]
                        + red[((mt + 4)*4 + r)*64 + lane]
                        + red[((mt + 8)*4 + r)*64 + lane]
                        + red[((mt +12)*4 + r)*64 + lane];
                float v = S + ipb[d];
                h0st[r] = v; h1st[r] = v;
                bf16 vb = __float2bfloat16(v);
                int row = m0 + q*4 + r;
                h0b3[row*DH + d] = vb;     // slot 0
                h1b[row*DH + d] = vb;      // buf 0
            }
        }
        __syncthreads();   // red region about to be overwritten by weights
    }

    // ---- weights -> LDS, XOR-swizzled rows (9216 chunks / 1024 thr = 9)
#pragma unroll
    for (int i = 0; i < 9; ++i) {
        int c = tid + 1024*i;
        int mi = c / 3072, rem = c % 3072;
        int gg = rem >> 10, r = (rem >> 6) & 15, kg = rem & 63;
        const bf16* base = (mi == 0) ? w0h : (mi == 1) ? w1h : w1i;
        const bf16* src = base + ((size_t)(gg*DH + d0 + r))*DH + kg*8;
        int dst = mi*49152 + gg*16384 + r*1024 + ((kg*16) ^ ((r & 7) << 4));
        *reinterpret_cast<bf16x8*>(smem + dst) = ldg8(src);
    }

    // ---- P0b: gi_s = x_s @ w_ih0^T (s=1..3), gate-local, kept in regs
    f32x4 gi1 = zero4, gi2 = zero4, gi3 = zero4;
    if (g < 3) {
        const bf16* wiR = w0i + (size_t)(g*DH + d0 + lr)*DH + q*8;
#pragma unroll
        for (int s = 1; s < 4; ++s) {
            const bf16* xr = xemb + (size_t)((s-1)*B64 + m0 + lr)*DH + q*8;
            f32x4 a = zero4;
#pragma unroll
            for (int k0 = 0; k0 < DH; k0 += 32)
                a = mfma16(ldg8(xr + k0), ldg8(wiR + k0), a);
            if (s == 1) gi1 = a; else if (s == 2) gi2 = a; else gi3 = a;
        }
    }
    gridbar(bar, 0);

    // ---- 4 steps x 2 layers; h0 triple-buffered, h1 double-buffered
    int c1 = 0;
#pragma unroll
    for (int s = 0; s < NSTEP; ++s) {
        int rsl = s % 3, rsw = (s + 1) % 3;
        f32x4 giv = (s == 0) ? zero4 : (s == 1) ? gi1 : (s == 2) ? gi2 : gi3;
        f32x4 aN = zero4;
        // layer 0: gh = h0 @ w0h^T (LDS weights)
        if (g < 3) {
            const bf16* hr = h0b3 + (size_t)rsl*HSZ + (size_t)(m0 + lr)*DH + q*8;
            int bbase = g*16384 + lr*1024;
            f32x4 a = zero4;
#pragma unroll
            for (int k0 = 0; k0 < DH; k0 += 32) {
                int off = (k0*2 + q*16) ^ ((lr & 7) << 4);
                a = mfma16(ldg8(hr + k0),
                           *reinterpret_cast<const bf16x8*>(smem + bbase + off), a);
            }
            if (g < 2) {
#pragma unroll
                for (int r = 0; r < 4; ++r)
                    sG[((g*4 + mt)*4 + r)*64 + lane] = a[r] + giv[r];
            } else aN = a;
        }
        __syncthreads();
        if (g == 2) {
#pragma unroll
            for (int r = 0; r < 4; ++r) {
                float G0 = sG[((0*4 + mt)*4 + r)*64 + lane];
                float G1 = sG[((1*4 + mt)*4 + r)*64 + lane];
                float rg = sigmf(G0 + bR0);
                float zg = sigmf(G1 + bZ0);
                float ng = tanhf(giv[r] + biN0 + rg * (aN[r] + bhN0));
                h0st[r] = (1.f - zg) * ng + zg * h0st[r];
                h0b3[(size_t)rsw*HSZ + (m0 + q*4 + r)*DH + d] = __float2bfloat16(h0st[r]);
            }
        }
        gridbar(bar, 1 + s);
        // layer 1: gates = h1 @ w1h^T + h0new @ w1i^T (LDS weights)
        f32x4 aH = zero4, aI = zero4;
        if (g < 3) {
            const bf16* h1r = h1b  + (size_t)c1 *HSZ + (size_t)(m0 + lr)*DH + q*8;
            const bf16* h0r = h0b3 + (size_t)rsw*HSZ + (size_t)(m0 + lr)*DH + q*8;
            int bH = 49152 + g*16384 + lr*1024;
            int bI = 98304 + g*16384 + lr*1024;
#pragma unroll
            for (int k0 = 0; k0 < DH; k0 += 32) {
                int off = (k0*2 + q*16) ^ ((lr & 7) << 4);
                aH = mfma16(ldg8(h1r + k0),
                            *reinterpret_cast<const bf16x8*>(smem + bH + off), aH);
                aI = mfma16(ldg8(h0r + k0),
                            *reinterpret_cast<const bf16x8*>(smem + bI + off), aI);
            }
            if (g < 2) {
#pragma unroll
                for (int r = 0; r < 4; ++r)
                    sG[((g*4 + mt)*4 + r)*64 + lane] = aH[r] + aI[r];
            }
        }
        __syncthreads();
        if (g == 2) {
#pragma unroll
            for (int r = 0; r < 4; ++r) {
                float G0 = sG[((0*4 + mt)*4 + r)*64 + lane];
                float G1 = sG[((1*4 + mt)*4 + r)*64 + lane];
                float rg = sigmf(G0 + bR1);
                float zg = sigmf(G1 + bZ1);
                float ng = tanhf(aI[r] + biN1 + rg * (aH[r] + bhN1));
                h1st[r] = (1.f - zg) * ng + zg * h1st[r];
                bf16 hvb = __float2bfloat16(h1st[r]);
                int row = m0 + q*4 + r;
                h1b[(size_t)(c1 ^ 1)*HSZ + row*DH + d] = hvb;
                hbig[(size_t)(row*NSTEP + s)*DH + d] = hvb;
            }
        }
        c1 ^= 1;
        __syncthreads();   // sG WAR before next step's layer-0 writes
    }
}

// ---------------------------------------------------------------------------
// k_logits v4: out(256x50257) = Hbig(256x512 bf16) @ out_w(50257x512 f32)^T
// 786 blocks x 512 thr = 8 waves. Wave = (m-quarter, n-chunk32): acc 2x16 =
// 32 VGPR -> ~24 waves/CU (3 blocks/CU). B-fragments prefetched 4-ahead per
// stage to break the L2/L3 load->MFMA dependence chain. A staged in
// XOR-swizzled LDS (conflict-free).
// ---------------------------------------------------------------------------
__global__ __launch_bounds__(512) void k_logits(
    const bf16* __restrict__ hbig, const float* __restrict__ outw, float* __restrict__ out)
{
    __shared__ __align__(16) bf16 sA[256 * 64];
    int t = threadIdx.x, w = t >> 6, lane = t & 63;
    int l32 = lane & 31, e = lane >> 5;
    int mq = w >> 1;                         // m-quarter (64 rows each)
    int n = blockIdx.x * 64 + (w & 1) * 32 + l32;
    int nr = n < VOC ? n : VOC - 1;
    const float* brow = outw + (size_t)nr * DH;

    f32x16 acc[2];
#pragma unroll
    for (int i = 0; i < 2; ++i)
#pragma unroll
        for (int j = 0; j < 16; ++j) acc[i][j] = 0.f;

    for (int k0 = 0; k0 < DH; k0 += 64) {
        // stage A[0:256][k0:k0+64] -> LDS, XOR-swizzled 16B groups
#pragma unroll
        for (int i = 0; i < 4; ++i) {
            int c = i * 512 + t;
            int m = c >> 3, j = c & 7;
            *reinterpret_cast<bf16x8*>(&sA[m * 64 + ((j ^ (m & 7)) << 3)]) =
                ldg8(hbig + (size_t)m * DH + k0 + j * 8);
        }
        __syncthreads();
        // prefetch all 4 B-fragments for this stage (independent loads)
        bf16x8 bf[4];
#pragma unroll
        for (int kk = 0; kk < 4; ++kk)
            bf[kk] = cvt8(brow + k0 + kk * 16 + e * 8);
#pragma unroll
        for (int kk = 0; kk < 4; ++kk) {
            int g = kk * 2 + e;
#pragma unroll
            for (int mt2 = 0; mt2 < 2; ++mt2) {
                int r = mq * 64 + mt2 * 32 + l32;
                bf16x8 afrag = *reinterpret_cast<const bf16x8*>(
                    &sA[r * 64 + ((g ^ (r & 7)) << 3)]);
                acc[mt2] = __builtin_amdgcn_mfma_f32_32x32x16_bf16(afrag, bf[kk], acc[mt2], 0, 0, 0);
            }
        }
        __syncthreads();
    }
    if (n < VOC) {
#pragma unroll
        for (int mt2 = 0; mt2 < 2; ++mt2)
#pragma unroll
            for (int reg = 0; reg < 16; ++reg) {
                int m = mq * 64 + mt2 * 32 + (reg & 3) + 8 * (reg >> 2) + 4 * e;
                out[(size_t)m * VOC + n] = acc[mt2][reg];
            }
    }
}

// ---------------------------------------------------------------------------
extern "C" void kernel_launch(void* const* d_in, const int* in_sizes, int n_in,
                              void* d_out, int out_size, void* d_ws, size_t ws_size,
                              hipStream_t stream) {
    const float* hs   = (const float*)d_in[0];
    const int*   tids = (const int*)d_in[1];
    const float* ipw  = (const float*)d_in[2];
    const float* ipb  = (const float*)d_in[3];
    const float* wih0 = (const float*)d_in[4];
    const float* whh0 = (const float*)d_in[5];
    const float* bih0 = (const float*)d_in[6];
    const float* bhh0 = (const float*)d_in[7];
    const float* wih1 = (const float*)d_in[8];
    const float* whh1 = (const float*)d_in[9];
    const float* bih1 = (const float*)d_in[10];
    const float* bhh1 = (const float*)d_in[11];
    const float* embed = (const float*)d_in[12];
    const float* outw  = (const float*)d_in[13];
    float* out = (float*)d_out;

    char* ws = (char*)d_ws;
    int*  bar  = (int*) (ws + 0);          // bars 0..4; memset below
    bf16* hsb  = (bf16*)(ws + 1024);       // 64x4096        (524288 B)
    bf16* ipwb = (bf16*)(ws + 525312);     // 512x4096       (4194304 B)
    bf16* w0i  = (bf16*)(ws + 4719616);    // 1536x512       (1572864 B each)
    bf16* w0h  = (bf16*)(ws + 6292480);
    bf16* w1i  = (bf16*)(ws + 7865344);
    bf16* w1h  = (bf16*)(ws + 9438208);
    bf16* xemb = (bf16*)(ws + 11011072);   // 3x64x512       (196608 B)
    bf16* h0b3 = (bf16*)(ws + 11207680);   // [3][64x512]    (196608 B)
    bf16* h1b  = (bf16*)(ws + 11404288);   // [2][64x512]    (131072 B)
    bf16* hbig = (bf16*)(ws + 11535360);   // 256x512 bf16, row m = b*4+s

    hipMemsetAsync(bar, 0, 256, stream);

    k_prep<<<1368, 512, 0, stream>>>(hs, ipw, wih0, whh0, wih1, whh1, embed, tids,
                                     hsb, ipwb, w0i, w0h, w1i, w1h, xemb);

    k_rec<<<NRB, 1024, 0, stream>>>(hsb, ipwb, ipb,
                                    w0i, w0h, bih0, bhh0,
                                    w1i, w1h, bih1, bhh1,
                                    xemb, h0b3, h1b, hbig, bar);

    k_logits<<<(VOC + 63) / 64, 512, 0, stream>>>(hbig, outw, out);
}